// Round 7
// baseline (531.428 us; speedup 1.0000x reference)
//
#include <hip/hip_runtime.h>
#include <hip/hip_cooperative_groups.h>

namespace cg = cooperative_groups;

#define N_NODES 2048
#define N_EDGES 65536
#define NV 6
#define C 32
#define BLK 256

// ---------------------------------------------------------------------------
// ws layout (floats, contiguous): cnt[2048] | sum1|sum2|sum3 [65536 each]
//                                 | h1|h2|h3 [65536 each]
// One source of truth per phase (__device__ fns, gridDim-agnostic);
// used by BOTH the cooperative mega-kernel and the discrete fallback.
// ---------------------------------------------------------------------------

struct MegaArgs {
    const float* x; const float* ea; const int* src; const int* dst;
    const float* W1; const float* b1; const float* root1; const float* bias1;
    const float* W2; const float* b2; const float* root2; const float* bias2;
    const float* W3; const float* b3; const float* root3; const float* bias3;
    float* cnt; float* sum1; float* sum2; float* sum3;
    float* h1; float* h2; float* h3; float* out;
};

union SharedU {
    struct { float Wall[6 * 1024]; float hb[4][256]; } e23;  // 24KB + 4KB
    struct { float hj[64 * 33]; float hi[64 * 32]; } cbt;    // 8.25KB + 8KB
};

// P0: zero cnt + sum1..3 (contiguous from cnt)
__device__ __forceinline__ void zero_phase(float* __restrict__ cnt, int gtid, int nth) {
    for (int i = gtid; i < N_NODES + 3 * N_NODES * C; i += nth) cnt[i] = 0.0f;
}

// P1: layer-1 edge messages + scatter + degree count (in_c = 1)
__device__ __forceinline__ void edge1_phase(const MegaArgs& a, int gtid, int nth) {
    for (int t = gtid; t < N_EDGES * C; t += nth) {
        const int e = t >> 5, o = t & 31;
        const float* eap = a.ea + e * NV;
        float wv = a.b1[o];
#pragma unroll
        for (int v = 0; v < NV; v++) wv = fmaf(eap[v], a.W1[v * C + o], wv);
        wv = fmaxf(wv, 0.0f);
        const int d = a.dst[e];
        atomicAdd(&a.sum1[d * C + o], a.x[a.src[e]] * wv);
        if (o == 0) atomicAdd(&a.cnt[d], 1.0f);
    }
}

// h_out = relu(sum/max(cnt,1) + hprev@root + bias)
template <int IN_C>
__device__ __forceinline__ void node_phase(const float* __restrict__ sum,
                                           const float* __restrict__ cnt,
                                           const float* __restrict__ hprev,
                                           const float* __restrict__ root,
                                           const float* __restrict__ bias,
                                           float* __restrict__ hout, int gtid, int nth) {
    for (int t = gtid; t < N_NODES * C; t += nth) {
        const int n = t >> 5, o = t & 31;
        const float inv = 1.0f / fmaxf(cnt[n], 1.0f);
        float acc = fmaf(sum[t], inv, bias[o]);
#pragma unroll
        for (int i = 0; i < IN_C; i++) acc = fmaf(hprev[n * IN_C + i], root[i * C + o], acc);
        hout[t] = fmaxf(acc, 0.0f);
    }
}

// Layers 2/3 edge phase (R4/R5-proven): wave per 8-edge group.
// lane l: o=l&31, half=l>>5, i-slice [half*16,+16). W in LDS stride-32
// (2-way half-wave alias = free, 0 conflicts measured). h staged per-wave:
// one contiguous 1KB b128 write, broadcast b128 reads.
__device__ __forceinline__ void edge23_phase(SharedU& sh,
                                             const float* __restrict__ hprev,
                                             const float* __restrict__ ea,
                                             const int* __restrict__ src,
                                             const int* __restrict__ dst,
                                             const float* __restrict__ W,
                                             const float* __restrict__ b,
                                             float* __restrict__ sumout) {
    float* Wall = sh.e23.Wall;
    for (int i = threadIdx.x; i < 6 * 1024; i += BLK) Wall[i] = W[i];
    __syncthreads();

    const int lane = threadIdx.x & 63;
    const int o = lane & 31;
    const int half = lane >> 5;
    const int i0 = half * 16;
    const int w = threadIdx.x >> 6;
    float* hbw = &sh.e23.hb[w][0];

    float breg[16];
#pragma unroll
    for (int j = 0; j < 16; j++) breg[j] = b[(i0 + j) * C + o];

    const int nw = (gridDim.x * BLK) >> 6;
    const int wid = (blockIdx.x * BLK + threadIdx.x) >> 6;
    for (int g = wid; g < N_EDGES / 8; g += nw) {
        const int e0 = g * 8;
        float eaf[48];
        const float4* eap4 = (const float4*)(ea + (size_t)e0 * NV);
#pragma unroll
        for (int t = 0; t < 12; t++) *(float4*)&eaf[t * 4] = eap4[t];

        const int4 sq = *(const int4*)&src[e0 + half * 4];
        float4 hq;
        hq.x = hprev[sq.x * C + o];
        hq.y = hprev[sq.y * C + o];
        hq.z = hprev[sq.z * C + o];
        hq.w = hprev[sq.w * C + o];
        *(float4*)&hbw[half * 128 + o * 4] = hq;  // contiguous 1KB wave write

        float acc[8] = {0, 0, 0, 0, 0, 0, 0, 0};
#pragma unroll
        for (int j = 0; j < 16; j++) {
            const int idx = (i0 + j) * C + o;
            const float w0 = Wall[idx];
            const float w1 = Wall[1024 + idx];
            const float w2 = Wall[2048 + idx];
            const float w3 = Wall[3072 + idx];
            const float w4 = Wall[4096 + idx];
            const float w5 = Wall[5120 + idx];
            const float bb = breg[j];
            const float4 hA = *(const float4*)&hbw[(i0 + j) * 4];
            const float4 hB = *(const float4*)&hbw[128 + (i0 + j) * 4];
            const float hv[8] = {hA.x, hA.y, hA.z, hA.w, hB.x, hB.y, hB.z, hB.w};
#pragma unroll
            for (int k = 0; k < 8; k++) {
                const float* eap = &eaf[k * 6];
                float t = bb;
                t = fmaf(eap[0], w0, t);
                t = fmaf(eap[1], w1, t);
                t = fmaf(eap[2], w2, t);
                t = fmaf(eap[3], w3, t);
                t = fmaf(eap[4], w4, t);
                t = fmaf(eap[5], w5, t);
                acc[k] = fmaf(hv[k], fmaxf(t, 0.0f), acc[k]);
            }
        }
#pragma unroll
        for (int k = 0; k < 8; k++) acc[k] += __shfl_down(acc[k], 32);

        const int4 dA = *(const int4*)&dst[e0];
        const int4 dB = *(const int4*)&dst[e0 + 4];
        if (lane < 32) {
            atomicAdd(&sumout[dA.x * C + o], acc[0]);
            atomicAdd(&sumout[dA.y * C + o], acc[1]);
            atomicAdd(&sumout[dA.z * C + o], acc[2]);
            atomicAdd(&sumout[dA.w * C + o], acc[3]);
            atomicAdd(&sumout[dB.x * C + o], acc[4]);
            atomicAdd(&sumout[dB.y * C + o], acc[5]);
            atomicAdd(&sumout[dB.z * C + o], acc[6]);
            atomicAdd(&sumout[dB.w * C + o], acc[7]);
        }
    }
}

// CBT: out[i,j] = sum_k |h[i,k]-h[j,k]|; 1024 64x64 tiles, gridDim-agnostic.
__device__ __forceinline__ void cbt_phase(SharedU& sh, const float* __restrict__ h,
                                          float* __restrict__ out) {
    const int lane = threadIdx.x & 63;
    const int w = threadIdx.x >> 6;
    for (int T = blockIdx.x; T < 1024; T += gridDim.x) {
        const int j0 = (T & 31) * 64;
        const int i0 = (T >> 5) * 64;
        __syncthreads();  // protect LDS reuse across tiles
        for (int t = threadIdx.x; t < 64 * 32; t += BLK) {
            sh.cbt.hj[(t >> 5) * 33 + (t & 31)] = h[j0 * 32 + t];
            sh.cbt.hi[t] = h[i0 * 32 + t];
        }
        __syncthreads();
        float hjr[32];
#pragma unroll
        for (int k = 0; k < 32; k++) hjr[k] = sh.cbt.hj[lane * 33 + k];
        const int j = j0 + lane;
#pragma unroll 4
        for (int ii = w * 16; ii < w * 16 + 16; ii++) {
            float acc = 0.0f;
#pragma unroll
            for (int k = 0; k < 32; k++) acc += fabsf(sh.cbt.hi[ii * 32 + k] - hjr[k]);
            out[(size_t)(i0 + ii) * N_NODES + j] = acc;
        }
    }
}

// ---------------- cooperative mega-kernel (1 dispatch) ----------------
__global__ __launch_bounds__(BLK, 2) void mega_kernel(MegaArgs a) {
    __shared__ SharedU sh;
    cg::grid_group grid = cg::this_grid();
    const int nth = gridDim.x * BLK;
    const int gtid = blockIdx.x * BLK + threadIdx.x;

    zero_phase(a.cnt, gtid, nth);
    grid.sync();
    edge1_phase(a, gtid, nth);
    grid.sync();
    node_phase<1>(a.sum1, a.cnt, a.x, a.root1, a.bias1, a.h1, gtid, nth);
    grid.sync();
    edge23_phase(sh, a.h1, a.ea, a.src, a.dst, a.W2, a.b2, a.sum2);
    grid.sync();
    node_phase<C>(a.sum2, a.cnt, a.h1, a.root2, a.bias2, a.h2, gtid, nth);
    grid.sync();
    edge23_phase(sh, a.h2, a.ea, a.src, a.dst, a.W3, a.b3, a.sum3);
    grid.sync();
    node_phase<C>(a.sum3, a.cnt, a.h2, a.root3, a.bias3, a.h3, gtid, nth);
    grid.sync();
    cbt_phase(sh, a.h3, a.out);
}

// ---------------- discrete fallback wrappers (R5-proven path) ----------------
__global__ __launch_bounds__(BLK) void k_edge1(MegaArgs a) {
    edge1_phase(a, blockIdx.x * BLK + threadIdx.x, gridDim.x * BLK);
}
template <int IN_C>
__global__ __launch_bounds__(BLK) void k_node(const float* sum, const float* cnt,
                                              const float* hprev, const float* root,
                                              const float* bias, float* hout) {
    node_phase<IN_C>(sum, cnt, hprev, root, bias, hout,
                     blockIdx.x * BLK + threadIdx.x, gridDim.x * BLK);
}
__global__ __launch_bounds__(BLK) void k_edge23(MegaArgs a, const float* hprev,
                                                const float* W, const float* b,
                                                float* sumout) {
    __shared__ SharedU sh;
    edge23_phase(sh, hprev, a.ea, a.src, a.dst, W, b, sumout);
}
__global__ __launch_bounds__(BLK) void k_cbt(const float* h, float* out) {
    __shared__ SharedU sh;
    cbt_phase(sh, h, out);
}

extern "C" void kernel_launch(void* const* d_in, const int* in_sizes, int n_in,
                              void* d_out, int out_size, void* d_ws, size_t ws_size,
                              hipStream_t stream) {
    float* ws = (float*)d_ws;
    MegaArgs a;
    a.x     = (const float*)d_in[0];
    a.ea    = (const float*)d_in[1];
    a.src   = (const int*)d_in[2];
    a.dst   = (const int*)d_in[2] + N_EDGES;
    a.W1    = (const float*)d_in[3];
    a.b1    = (const float*)d_in[4];
    a.root1 = (const float*)d_in[5];
    a.bias1 = (const float*)d_in[6];
    a.W2    = (const float*)d_in[7];
    a.b2    = (const float*)d_in[8];
    a.root2 = (const float*)d_in[9];
    a.bias2 = (const float*)d_in[10];
    a.W3    = (const float*)d_in[11];
    a.b3    = (const float*)d_in[12];
    a.root3 = (const float*)d_in[13];
    a.bias3 = (const float*)d_in[14];
    a.cnt  = ws;
    a.sum1 = ws + N_NODES;
    a.sum2 = a.sum1 + N_NODES * C;
    a.sum3 = a.sum2 + N_NODES * C;
    a.h1   = a.sum3 + N_NODES * C;
    a.h2   = a.h1 + N_NODES * C;
    a.h3   = a.h2 + N_NODES * C;
    a.out  = (float*)d_out;

    void* kp[] = {&a};
    // Deterministic cascade: coop@512 -> coop@256 -> discrete (R5 path).
    hipError_t err = hipLaunchCooperativeKernel((const void*)mega_kernel,
                                                dim3(512), dim3(BLK), kp, 0, stream);
    if (err != hipSuccess) {
        (void)hipGetLastError();  // clear sticky error
        err = hipLaunchCooperativeKernel((const void*)mega_kernel,
                                         dim3(256), dim3(BLK), kp, 0, stream);
    }
    if (err != hipSuccess) {
        (void)hipGetLastError();
        hipMemsetAsync(d_ws, 0,
                       (size_t)(N_NODES + 3 * N_NODES * C) * sizeof(float), stream);
        k_edge1<<<(N_EDGES * C) / BLK, BLK, 0, stream>>>(a);
        k_node<1><<<(N_NODES * C) / BLK, BLK, 0, stream>>>(a.sum1, a.cnt, a.x, a.root1, a.bias1, a.h1);
        k_edge23<<<512, BLK, 0, stream>>>(a, a.h1, a.W2, a.b2, a.sum2);
        k_node<C><<<(N_NODES * C) / BLK, BLK, 0, stream>>>(a.sum2, a.cnt, a.h1, a.root2, a.bias2, a.h2);
        k_edge23<<<512, BLK, 0, stream>>>(a, a.h2, a.W3, a.b3, a.sum3);
        k_node<C><<<(N_NODES * C) / BLK, BLK, 0, stream>>>(a.sum3, a.cnt, a.h2, a.root3, a.bias3, a.h3);
        k_cbt<<<512, BLK, 0, stream>>>(a.h3, a.out);
    }
}

// Round 9
// 194.349 us; speedup vs baseline: 2.7344x; 2.7344x over previous
//
#include <hip/hip_runtime.h>

#define N_NODES 2048
#define N_EDGES 65536
#define NV 6
#define C 32
#define BLK 256

// ---------------------------------------------------------------------------
// ws layout (ints then floats, 16B-aligned):
//   cnt_i[2048] cursor[2048] (zeroed via 16KB memset) rowptr[2049] pad
//   eid[65536] | msg[E*32] h1 h2 h3 [N*32 each]
// dst is identical for all 3 layers -> CSR built once per call.
// NO global atomics in the hot path.
// ---------------------------------------------------------------------------

__global__ void hist_kernel(const int* __restrict__ dst, int* __restrict__ cnt) {
    int e = blockIdx.x * blockDim.x + threadIdx.x;
    if (e < N_EDGES) atomicAdd(&cnt[dst[e]], 1);
}

__global__ __launch_bounds__(256) void scan_kernel(const int* __restrict__ cnt,
                                                   int* __restrict__ rowptr) {
    __shared__ int part[256];
    const int tid = threadIdx.x;
    int local[8];
    int s = 0;
#pragma unroll
    for (int k = 0; k < 8; k++) { local[k] = cnt[tid * 8 + k]; s += local[k]; }
    part[tid] = s;
    __syncthreads();
    for (int off = 1; off < 256; off <<= 1) {
        int v = (tid >= off) ? part[tid - off] : 0;
        __syncthreads();
        part[tid] += v;
        __syncthreads();
    }
    int run = part[tid] - s;  // exclusive prefix
#pragma unroll
    for (int k = 0; k < 8; k++) { rowptr[tid * 8 + k] = run; run += local[k]; }
    if (tid == 255) rowptr[2048] = run;  // == N_EDGES
}

__global__ void scatter_kernel(const int* __restrict__ dst, const int* __restrict__ rowptr,
                               int* __restrict__ cursor, int* __restrict__ eid) {
    int e = blockIdx.x * blockDim.x + threadIdx.x;
    if (e < N_EDGES) {
        int d = dst[e];
        int pos = atomicAdd(&cursor[d], 1);
        eid[rowptr[d] + pos] = e;
    }
}

// ---- Layer 1, fully fused (no edge pass, no sum buffer, no atomics):
// wave per node; lane = p*32+o (p in {0,1} splits the edge list).
__global__ __launch_bounds__(BLK) void layer1_kernel(
    const float* __restrict__ x, const float* __restrict__ ea,
    const int* __restrict__ src, const int* __restrict__ rowptr,
    const int* __restrict__ eid,
    const float* __restrict__ W1, const float* __restrict__ b1,
    const float* __restrict__ root1, const float* __restrict__ bias1,
    float* __restrict__ h1) {
    const int lane = threadIdx.x & 63;
    const int o = lane & 31;
    const int p = lane >> 5;
    const int n = blockIdx.x * 4 + (threadIdx.x >> 6);
    float w1r[NV];
#pragma unroll
    for (int v = 0; v < NV; v++) w1r[v] = W1[v * C + o];
    const float b1o = b1[o];
    const int beg = rowptr[n], end = rowptr[n + 1];
    float acc = 0.0f;
    for (int k = beg + p; k < end; k += 2) {
        const int e = eid[k];
        const float xs = x[src[e]];
        const float* eap = ea + e * NV;
        float t = b1o;
#pragma unroll
        for (int v = 0; v < NV; v++) t = fmaf(eap[v], w1r[v], t);
        acc = fmaf(xs, fmaxf(t, 0.0f), acc);
    }
    acc += __shfl_down(acc, 32);
    if (lane < 32) {
        const float inv = 1.0f / fmaxf((float)(end - beg), 1.0f);
        float r = fmaf(acc, inv, bias1[o]);
        r = fmaf(x[n], root1[o], r);
        h1[n * C + o] = fmaxf(r, 0.0f);
    }
}

// ---- Layers 2/3 edge messages (R5-proven W-in-registers core; coalesced
// msg stores, no atomics). Wave per 8-edge group, 4 groups/wave.
__global__ __launch_bounds__(BLK) void edge23_kernel(
    const float* __restrict__ hprev,   // [N, 32]
    const float* __restrict__ ea,      // [E, 6]
    const int* __restrict__ src,
    const float* __restrict__ W,       // [NV, 1024]
    const float* __restrict__ b,       // [1024]
    float* __restrict__ msg)           // [E, 32]
{
    __shared__ float hb[4][256];
    const int lane = threadIdx.x & 63;
    const int o = lane & 31;
    const int half = lane >> 5;
    const int i0 = half * 16;
    const int w = threadIdx.x >> 6;
    float* hbw = &hb[w][0];

    float wreg[16][6], breg[16];
#pragma unroll
    for (int j = 0; j < 16; j++) {
#pragma unroll
        for (int v = 0; v < 6; v++) wreg[j][v] = W[v * 1024 + (i0 + j) * C + o];
        breg[j] = b[(i0 + j) * C + o];
    }

    const int wid = (blockIdx.x * BLK + threadIdx.x) >> 6;  // 0..2047
    for (int g = wid; g < N_EDGES / 8; g += 2048) {
        const int e0 = g * 8;
        const int4 sq = *(const int4*)&src[e0 + half * 4];
        float4 hq;
        hq.x = hprev[sq.x * C + o];
        hq.y = hprev[sq.y * C + o];
        hq.z = hprev[sq.z * C + o];
        hq.w = hprev[sq.w * C + o];
        *(float4*)&hbw[half * 128 + o * 4] = hq;  // contiguous 1KB wave write

        float accs[8];
        const float4* eap4 = (const float4*)(ea + (size_t)e0 * NV);
#pragma unroll
        for (int sub = 0; sub < 2; sub++) {
            float eaf[24];
#pragma unroll
            for (int t = 0; t < 6; t++) *(float4*)&eaf[t * 4] = eap4[sub * 6 + t];
            float a0 = 0.0f, a1 = 0.0f, a2 = 0.0f, a3 = 0.0f;
#pragma unroll
            for (int j = 0; j < 16; j++) {
                const float4 hA = *(const float4*)&hbw[sub * 128 + (i0 + j) * 4];
                const float bb = breg[j];
                const float w0 = wreg[j][0], w1 = wreg[j][1], w2 = wreg[j][2];
                const float w3 = wreg[j][3], w4 = wreg[j][4], w5 = wreg[j][5];
                float t0 = bb, t1 = bb, t2 = bb, t3 = bb;
                t0 = fmaf(eaf[0],  w0, t0); t1 = fmaf(eaf[6],  w0, t1);
                t2 = fmaf(eaf[12], w0, t2); t3 = fmaf(eaf[18], w0, t3);
                t0 = fmaf(eaf[1],  w1, t0); t1 = fmaf(eaf[7],  w1, t1);
                t2 = fmaf(eaf[13], w1, t2); t3 = fmaf(eaf[19], w1, t3);
                t0 = fmaf(eaf[2],  w2, t0); t1 = fmaf(eaf[8],  w2, t1);
                t2 = fmaf(eaf[14], w2, t2); t3 = fmaf(eaf[20], w2, t3);
                t0 = fmaf(eaf[3],  w3, t0); t1 = fmaf(eaf[9],  w3, t1);
                t2 = fmaf(eaf[15], w3, t2); t3 = fmaf(eaf[21], w3, t3);
                t0 = fmaf(eaf[4],  w4, t0); t1 = fmaf(eaf[10], w4, t1);
                t2 = fmaf(eaf[16], w4, t2); t3 = fmaf(eaf[22], w4, t3);
                t0 = fmaf(eaf[5],  w5, t0); t1 = fmaf(eaf[11], w5, t1);
                t2 = fmaf(eaf[17], w5, t2); t3 = fmaf(eaf[23], w5, t3);
                a0 = fmaf(hA.x, fmaxf(t0, 0.0f), a0);
                a1 = fmaf(hA.y, fmaxf(t1, 0.0f), a1);
                a2 = fmaf(hA.z, fmaxf(t2, 0.0f), a2);
                a3 = fmaf(hA.w, fmaxf(t3, 0.0f), a3);
            }
            accs[sub * 4 + 0] = a0; accs[sub * 4 + 1] = a1;
            accs[sub * 4 + 2] = a2; accs[sub * 4 + 3] = a3;
        }
#pragma unroll
        for (int k = 0; k < 8; k++) accs[k] += __shfl_down(accs[k], 32);
        if (lane < 32) {
            float* mp = msg + (size_t)e0 * C + o;
#pragma unroll
            for (int k = 0; k < 8; k++) mp[k * C] = accs[k];  // 8x coalesced 128B
        }
    }
}

// ---- Gather + node update (layers 2/3): wave per node, lane = p*32+o.
// h_out = relu(mean(msg over in-edges) + hprev@root + bias). No atomics.
// BOUNDARY FIX vs R8: unrolled body reads k,k+2,k+4,k+6 -> requires
// k+7 <= end (k+6 <= end-1). R8's `k+6 <= end` read eid[end] (next node's
// first edge) for certain degree residues -> absmax 0.273.
__global__ __launch_bounds__(BLK) void gather_kernel(
    const float* __restrict__ msg, const int* __restrict__ rowptr,
    const int* __restrict__ eid, const float* __restrict__ hprev,
    const float* __restrict__ root,   // [32, 32]
    const float* __restrict__ bias,   // [32]
    float* __restrict__ hout) {       // [N, 32]
    const int lane = threadIdx.x & 63;
    const int o = lane & 31;
    const int p = lane >> 5;
    const int n = blockIdx.x * 4 + (threadIdx.x >> 6);
    const int beg = rowptr[n], end = rowptr[n + 1];
    float acc = 0.0f;
    int k = beg + p;
    for (; k + 7 <= end; k += 8) {  // accesses k,k+2,k+4,k+6; all <= end-1
        int ka = eid[k], kb = eid[k + 2], kc = eid[k + 4], kd = eid[k + 6];
        float m0 = msg[ka * C + o];
        float m1 = msg[kb * C + o];
        float m2 = msg[kc * C + o];
        float m3 = msg[kd * C + o];
        acc += (m0 + m1) + (m2 + m3);
    }
    for (; k < end; k += 2) acc += msg[eid[k] * C + o];
    acc += __shfl_down(acc, 32);
    if (lane < 32) {
        const float inv = 1.0f / fmaxf((float)(end - beg), 1.0f);
        float r = fmaf(acc, inv, bias[o]);
#pragma unroll
        for (int i = 0; i < C; i++) r = fmaf(hprev[n * C + i], root[i * C + o], r);
        hout[n * C + o] = fmaxf(r, 0.0f);
    }
}

// ---- CBT: out[i,j] = sum_k |h[i,k]-h[j,k]| (R5-proven)
__global__ __launch_bounds__(BLK) void cbt_kernel(const float* __restrict__ h,
                                                  float* __restrict__ out) {
    __shared__ float hj_s[64][33];
    __shared__ float hi_s[64 * 32];
    const int lane = threadIdx.x & 63;
    const int w = threadIdx.x >> 6;
    const int j0 = blockIdx.x * 64;
    const int i0 = blockIdx.y * 64;
    for (int t = threadIdx.x; t < 64 * 32; t += BLK) {
        hj_s[t >> 5][t & 31] = h[j0 * 32 + t];
        hi_s[t] = h[i0 * 32 + t];
    }
    __syncthreads();
    float hj[32];
#pragma unroll
    for (int k = 0; k < 32; k++) hj[k] = hj_s[lane][k];
    const int j = j0 + lane;
#pragma unroll 4
    for (int ii = w * 16; ii < w * 16 + 16; ii++) {
        float acc = 0.0f;
#pragma unroll
        for (int k = 0; k < 32; k++) acc += fabsf(hi_s[ii * 32 + k] - hj[k]);
        out[(size_t)(i0 + ii) * N_NODES + j] = acc;
    }
}

extern "C" void kernel_launch(void* const* d_in, const int* in_sizes, int n_in,
                              void* d_out, int out_size, void* d_ws, size_t ws_size,
                              hipStream_t stream) {
    const float* x         = (const float*)d_in[0];
    const float* edge_attr = (const float*)d_in[1];
    const int*   edge_idx  = (const int*)d_in[2];
    const float* W1 = (const float*)d_in[3];
    const float* b1 = (const float*)d_in[4];
    const float* root1 = (const float*)d_in[5];
    const float* bias1 = (const float*)d_in[6];
    const float* W2 = (const float*)d_in[7];
    const float* b2 = (const float*)d_in[8];
    const float* root2 = (const float*)d_in[9];
    const float* bias2 = (const float*)d_in[10];
    const float* W3 = (const float*)d_in[11];
    const float* b3 = (const float*)d_in[12];
    const float* root3 = (const float*)d_in[13];
    const float* bias3 = (const float*)d_in[14];

    const int* src = edge_idx;
    const int* dst = edge_idx + N_EDGES;

    int* wsi    = (int*)d_ws;
    int* cnt_i  = wsi;               // 2048
    int* cursor = wsi + 2048;        // 2048
    int* rowptr = wsi + 4096;        // 2049
    int* eid    = wsi + 6160;        // 65536 (6160 keeps 16B alignment)
    float* msg  = (float*)(wsi + 6160 + 65536);
    float* h1   = msg + (size_t)N_EDGES * C;
    float* h2   = h1 + N_NODES * C;
    float* h3   = h2 + N_NODES * C;

    // zero cnt_i + cursor (16 KB only)
    hipMemsetAsync(d_ws, 0, 4096 * sizeof(int), stream);

    // CSR build (dst shared by all layers)
    hist_kernel<<<N_EDGES / BLK, BLK, 0, stream>>>(dst, cnt_i);
    scan_kernel<<<1, 256, 0, stream>>>(cnt_i, rowptr);
    scatter_kernel<<<N_EDGES / BLK, BLK, 0, stream>>>(dst, rowptr, cursor, eid);

    // Layer 1: fully fused gather (no edge pass, no atomics)
    layer1_kernel<<<N_NODES / 4, BLK, 0, stream>>>(x, edge_attr, src, rowptr, eid,
                                                   W1, b1, root1, bias1, h1);
    // Layer 2
    edge23_kernel<<<512, BLK, 0, stream>>>(h1, edge_attr, src, W2, b2, msg);
    gather_kernel<<<N_NODES / 4, BLK, 0, stream>>>(msg, rowptr, eid, h1, root2, bias2, h2);
    // Layer 3
    edge23_kernel<<<512, BLK, 0, stream>>>(h2, edge_attr, src, W3, b3, msg);
    gather_kernel<<<N_NODES / 4, BLK, 0, stream>>>(msg, rowptr, eid, h2, root3, bias3, h3);

    // CBT
    cbt_kernel<<<dim3(N_NODES / 64, N_NODES / 64), BLK, 0, stream>>>(h3, (float*)d_out);
}

// Round 10
// 166.646 us; speedup vs baseline: 3.1890x; 1.1662x over previous
//
#include <hip/hip_runtime.h>

#define N_NODES 2048
#define N_EDGES 65536
#define NV 6
#define C 32
#define BLK 256

// ---------------------------------------------------------------------------
// ws layout (floats): cnt[2048] | sum1|sum2|sum3 [65536 each] | h1|h2|h3.
// memset zeroes only cnt+sum1 (270 KB); sum2/sum3 are zeroed inside edge1
// (disjoint from its sum1 atomics; readers are 2+ dispatches later).
// R9 lesson: L2-resident atomic scatter BEATS dense msg round-trip -- keep it.
// ---------------------------------------------------------------------------

// Layer 1 (in_c = 1), degree count fused (o==0 lane), sum2/3 zeroing fused.
__global__ void edge1_kernel(const float* __restrict__ x,
                             const float* __restrict__ ea,
                             const int* __restrict__ src,
                             const int* __restrict__ dst,
                             const float* __restrict__ W1,
                             const float* __restrict__ b1,
                             float* __restrict__ sum1,
                             float* __restrict__ sum23,   // sum2 base (2*N*C floats)
                             float* __restrict__ cnt) {
    int t = blockIdx.x * blockDim.x + threadIdx.x;
    if (t < 2 * N_NODES * C) sum23[t] = 0.0f;   // zero sum2+sum3 (idempotent)
    int e = t >> 5, o = t & 31;
    if (e >= N_EDGES) return;
    const float* eap = ea + e * NV;
    float w = b1[o];
#pragma unroll
    for (int v = 0; v < NV; v++) w = fmaf(eap[v], W1[v * C + o], w);
    w = fmaxf(w, 0.0f);
    int d = dst[e];
    atomicAdd(&sum1[d * C + o], x[src[e]] * w);
    if (o == 0) atomicAdd(&cnt[d], 1.0f);
}

// Finalize a layer: h_out = relu(sum/max(cnt,1) + h_prev @ root + bias)
template <int IN_C>
__global__ void node_kernel(const float* __restrict__ sum,
                            const float* __restrict__ cnt,
                            const float* __restrict__ hprev,
                            const float* __restrict__ root,  // [IN_C, C]
                            const float* __restrict__ bias,  // [C]
                            float* __restrict__ hout) {
    int t = blockIdx.x * blockDim.x + threadIdx.x;  // N*C threads
    int n = t >> 5, o = t & 31;
    float inv = 1.0f / fmaxf(cnt[n], 1.0f);
    float acc = sum[t] * inv + bias[o];
#pragma unroll
    for (int i = 0; i < IN_C; i++) acc = fmaf(hprev[n * IN_C + i], root[i * C + o], acc);
    hout[t] = fmaxf(acc, 0.0f);
}

// Layers 2/3 (R5 reg-W core + up-front 4-group h staging for MLP):
// lane l: o=l&31, half=l>>5, i-slice [half*16,+16); wreg[16][6]+breg[16]
// is exactly the lane's j-loop footprint. Wave owns groups wid+{0,2048,
// 4096,6144}; ALL 16 h-gather chains issue back-to-back up front (memory-
// level parallelism), staged per-wave per-group in LDS (contiguous 1KB b128
// writes, broadcast b128 reads -- 0 conflicts measured). unroll 2 lets
// consecutive groups' ea loads overlap the FMA block. VGPR capped at 256
// by launch_bounds(256,2) to hold 2 waves/SIMD.
__global__ __launch_bounds__(BLK, 2) void edge23_kernel(
    const float* __restrict__ hprev,   // [N, 32]
    const float* __restrict__ ea,      // [E, 6]
    const int* __restrict__ src,
    const int* __restrict__ dst,
    const float* __restrict__ W,       // [NV, 1024]
    const float* __restrict__ b,       // [1024]
    float* __restrict__ sumout)        // [N, 32]
{
    __shared__ float hb[4][4][256];    // [wave][group][...] = 16 KB
    const int lane = threadIdx.x & 63;
    const int o = lane & 31;
    const int half = lane >> 5;
    const int i0 = half * 16;
    const int w = threadIdx.x >> 6;

    float wreg[16][6], breg[16];
#pragma unroll
    for (int j = 0; j < 16; j++) {
#pragma unroll
        for (int v = 0; v < 6; v++) wreg[j][v] = W[v * 1024 + (i0 + j) * C + o];
        breg[j] = b[(i0 + j) * C + o];
    }

    const int wid = (blockIdx.x * BLK + threadIdx.x) >> 6;  // 0..2047

    // ---- stage h[src] for all 4 groups up front ----
    int4 sqs[4];
#pragma unroll
    for (int i = 0; i < 4; i++)
        sqs[i] = *(const int4*)&src[(wid + i * 2048) * 8 + half * 4];
#pragma unroll
    for (int i = 0; i < 4; i++) {
        float4 hq;
        hq.x = hprev[sqs[i].x * C + o];
        hq.y = hprev[sqs[i].y * C + o];
        hq.z = hprev[sqs[i].z * C + o];
        hq.w = hprev[sqs[i].w * C + o];
        *(float4*)&hb[w][i][half * 128 + o * 4] = hq;  // contiguous 1KB wave write
    }

#pragma unroll 2
    for (int i = 0; i < 4; i++) {
        const int e0 = (wid + i * 2048) * 8;
        const float* hbw = &hb[w][i][0];
        const float4* eap4 = (const float4*)(ea + (size_t)e0 * NV);
        float accs[8];
#pragma unroll
        for (int sub = 0; sub < 2; sub++) {
            float eaf[24];
#pragma unroll
            for (int t = 0; t < 6; t++) *(float4*)&eaf[t * 4] = eap4[sub * 6 + t];
            float a0 = 0.0f, a1 = 0.0f, a2 = 0.0f, a3 = 0.0f;
#pragma unroll
            for (int j = 0; j < 16; j++) {
                const float4 hA = *(const float4*)&hbw[sub * 128 + (i0 + j) * 4];
                const float bb = breg[j];
                const float w0 = wreg[j][0], w1 = wreg[j][1], w2 = wreg[j][2];
                const float w3 = wreg[j][3], w4 = wreg[j][4], w5 = wreg[j][5];
                float t0 = bb, t1 = bb, t2 = bb, t3 = bb;
                t0 = fmaf(eaf[0],  w0, t0); t1 = fmaf(eaf[6],  w0, t1);
                t2 = fmaf(eaf[12], w0, t2); t3 = fmaf(eaf[18], w0, t3);
                t0 = fmaf(eaf[1],  w1, t0); t1 = fmaf(eaf[7],  w1, t1);
                t2 = fmaf(eaf[13], w1, t2); t3 = fmaf(eaf[19], w1, t3);
                t0 = fmaf(eaf[2],  w2, t0); t1 = fmaf(eaf[8],  w2, t1);
                t2 = fmaf(eaf[14], w2, t2); t3 = fmaf(eaf[20], w2, t3);
                t0 = fmaf(eaf[3],  w3, t0); t1 = fmaf(eaf[9],  w3, t1);
                t2 = fmaf(eaf[15], w3, t2); t3 = fmaf(eaf[21], w3, t3);
                t0 = fmaf(eaf[4],  w4, t0); t1 = fmaf(eaf[10], w4, t1);
                t2 = fmaf(eaf[16], w4, t2); t3 = fmaf(eaf[22], w4, t3);
                t0 = fmaf(eaf[5],  w5, t0); t1 = fmaf(eaf[11], w5, t1);
                t2 = fmaf(eaf[17], w5, t2); t3 = fmaf(eaf[23], w5, t3);
                a0 = fmaf(hA.x, fmaxf(t0, 0.0f), a0);
                a1 = fmaf(hA.y, fmaxf(t1, 0.0f), a1);
                a2 = fmaf(hA.z, fmaxf(t2, 0.0f), a2);
                a3 = fmaf(hA.w, fmaxf(t3, 0.0f), a3);
            }
            accs[sub * 4 + 0] = a0; accs[sub * 4 + 1] = a1;
            accs[sub * 4 + 2] = a2; accs[sub * 4 + 3] = a3;
        }
#pragma unroll
        for (int k = 0; k < 8; k++) accs[k] += __shfl_down(accs[k], 32);

        const int4 dA = *(const int4*)&dst[e0];
        const int4 dB = *(const int4*)&dst[e0 + 4];
        if (lane < 32) {
            atomicAdd(&sumout[dA.x * C + o], accs[0]);
            atomicAdd(&sumout[dA.y * C + o], accs[1]);
            atomicAdd(&sumout[dA.z * C + o], accs[2]);
            atomicAdd(&sumout[dA.w * C + o], accs[3]);
            atomicAdd(&sumout[dB.x * C + o], accs[4]);
            atomicAdd(&sumout[dB.y * C + o], accs[5]);
            atomicAdd(&sumout[dB.z * C + o], accs[6]);
            atomicAdd(&sumout[dB.w * C + o], accs[7]);
        }
    }
}

// CBT: out[i,j] = sum_k |h[i,k]-h[j,k]|. 256-thread blocks, 64x64 tiles.
__global__ __launch_bounds__(BLK) void cbt_kernel(const float* __restrict__ h,
                                                  float* __restrict__ out) {
    __shared__ float hj_s[64][33];
    __shared__ float hi_s[64 * 32];
    const int lane = threadIdx.x & 63;
    const int w = threadIdx.x >> 6;
    const int j0 = blockIdx.x * 64;
    const int i0 = blockIdx.y * 64;
    for (int t = threadIdx.x; t < 64 * 32; t += BLK) {
        hj_s[t >> 5][t & 31] = h[j0 * 32 + t];
        hi_s[t] = h[i0 * 32 + t];
    }
    __syncthreads();
    float hj[32];
#pragma unroll
    for (int k = 0; k < 32; k++) hj[k] = hj_s[lane][k];
    const int j = j0 + lane;
#pragma unroll 4
    for (int ii = w * 16; ii < w * 16 + 16; ii++) {
        float acc = 0.0f;
#pragma unroll
        for (int k = 0; k < 32; k++) acc += fabsf(hi_s[ii * 32 + k] - hj[k]);
        out[(size_t)(i0 + ii) * N_NODES + j] = acc;
    }
}

extern "C" void kernel_launch(void* const* d_in, const int* in_sizes, int n_in,
                              void* d_out, int out_size, void* d_ws, size_t ws_size,
                              hipStream_t stream) {
    const float* x         = (const float*)d_in[0];
    const float* edge_attr = (const float*)d_in[1];
    const int*   edge_idx  = (const int*)d_in[2];
    const float* W1 = (const float*)d_in[3];
    const float* b1 = (const float*)d_in[4];
    const float* root1 = (const float*)d_in[5];
    const float* bias1 = (const float*)d_in[6];
    const float* W2 = (const float*)d_in[7];
    const float* b2 = (const float*)d_in[8];
    const float* root2 = (const float*)d_in[9];
    const float* bias2 = (const float*)d_in[10];
    const float* W3 = (const float*)d_in[11];
    const float* b3 = (const float*)d_in[12];
    const float* root3 = (const float*)d_in[13];
    const float* bias3 = (const float*)d_in[14];

    const int* src = edge_idx;            // row 0
    const int* dst = edge_idx + N_EDGES;  // row 1

    float* ws   = (float*)d_ws;
    float* cnt  = ws;
    float* sum1 = ws + N_NODES;
    float* sum2 = sum1 + N_NODES * C;
    float* sum3 = sum2 + N_NODES * C;
    float* h1   = sum3 + N_NODES * C;
    float* h2   = h1 + N_NODES * C;
    float* h3   = h2 + N_NODES * C;

    // zero cnt + sum1 only (270 KB); sum2/sum3 zeroed inside edge1
    hipMemsetAsync(d_ws, 0, (size_t)(N_NODES + N_NODES * C) * sizeof(float), stream);

    // Layer 1 (degree count + sum2/3 zeroing fused)
    edge1_kernel<<<(N_EDGES * C) / BLK, BLK, 0, stream>>>(x, edge_attr, src, dst,
                                                          W1, b1, sum1, sum2, cnt);
    node_kernel<1><<<(N_NODES * C) / BLK, BLK, 0, stream>>>(sum1, cnt, x, root1, bias1, h1);

    // Layer 2
    edge23_kernel<<<512, BLK, 0, stream>>>(h1, edge_attr, src, dst, W2, b2, sum2);
    node_kernel<C><<<(N_NODES * C) / BLK, BLK, 0, stream>>>(sum2, cnt, h1, root2, bias2, h2);

    // Layer 3
    edge23_kernel<<<512, BLK, 0, stream>>>(h2, edge_attr, src, dst, W3, b3, sum3);
    node_kernel<C><<<(N_NODES * C) / BLK, BLK, 0, stream>>>(sum3, cnt, h2, root3, bias3, h3);

    // CBT
    cbt_kernel<<<dim3(N_NODES / 64, N_NODES / 64), BLK, 0, stream>>>(h3, (float*)d_out);
}